// Round 2
// baseline (713.141 us; speedup 1.0000x reference)
//
#include <hip/hip_runtime.h>
#include <hip/hip_bf16.h>
#include <math.h>

#define N_NODES 50000
#define N_EDGES 800000
#define IN_DIM 128
#define OUT_DIM 64
#define NEG_SLOPE 0.01f

#define NPW 8            // nodes per wave (gemm)
#define NWAVES 4
#define NPB (NPW * NWAVES)  // 32 nodes per block

// Kernel 1: z = h @ fc_w.T ; also s_src[n]=z[n]·a_src, s_dst[n]=z[n]·a_dst.
// Native-layout padded weight tile in LDS (conflict-free b128 reads/writes).
// One wave computes 8 nodes: weight row read once, reused 8x.
__global__ __launch_bounds__(256) void gemm_scores_kernel(
    const float* __restrict__ h, const float* __restrict__ fc_w,
    const float* __restrict__ attn_w,
    float* __restrict__ z, float* __restrict__ s_src, float* __restrict__ s_dst)
{
    __shared__ float wlds[OUT_DIM][IN_DIM + 4];   // 64 x 132 floats = 33 KB
    __shared__ float hlds[NPB][IN_DIM];           // 32 x 128 floats = 16 KB

    const int tid  = threadIdx.x;
    const int wave = tid >> 6;
    const int lane = tid & 63;
    const int n0   = blockIdx.x * NPB;

    // stage fc_w (native layout, float4): 2048 vec4
    for (int idx = tid; idx < OUT_DIM * IN_DIM / 4; idx += 256) {
        int d  = idx >> 5;       // / (IN_DIM/4)
        int kc = idx & 31;
        float4 v = ((const float4*)fc_w)[idx];
        *(float4*)&wlds[d][kc * 4] = v;
    }
    // stage 32 h rows (float4): 1024 vec4
    for (int idx = tid; idx < NPB * IN_DIM / 4; idx += 256) {
        int r  = idx >> 5;
        int kc = idx & 31;
        int n  = n0 + r;
        float4 v = make_float4(0.f, 0.f, 0.f, 0.f);
        if (n < N_NODES) v = ((const float4*)h)[n * (IN_DIM / 4) + kc];
        *(float4*)&hlds[r][kc * 4] = v;
    }
    __syncthreads();

    const int rbase = wave * NPW;
    float acc[NPW];
#pragma unroll
    for (int r = 0; r < NPW; ++r) acc[r] = 0.f;

#pragma unroll
    for (int k4 = 0; k4 < IN_DIM / 4; ++k4) {
        const float4 wv = *(const float4*)&wlds[lane][k4 * 4];
#pragma unroll
        for (int r = 0; r < NPW; ++r) {
            const float4 hv = *(const float4*)&hlds[rbase + r][k4 * 4]; // uniform → broadcast
            acc[r] = fmaf(wv.x, hv.x, acc[r]);
            acc[r] = fmaf(wv.y, hv.y, acc[r]);
            acc[r] = fmaf(wv.z, hv.z, acc[r]);
            acc[r] = fmaf(wv.w, hv.w, acc[r]);
        }
    }

    const float asrc = attn_w[lane];
    const float adst = attn_w[OUT_DIM + lane];

#pragma unroll
    for (int r = 0; r < NPW; ++r) {
        const int n = n0 + rbase + r;
        if (n >= N_NODES) break;            // wave-uniform branch
        z[n * OUT_DIM + lane] = acc[r];
        float ps = acc[r] * asrc;
        float pd = acc[r] * adst;
#pragma unroll
        for (int off = 32; off; off >>= 1) {
            ps += __shfl_xor(ps, off);
            pd += __shfl_xor(pd, off);
        }
        if (lane == 0) { s_src[n] = ps; s_dst[n] = pd; }
    }
}

// Kernel 2: row_ptr[n] = lower_bound(dst, n)  (dst is sorted)
__global__ __launch_bounds__(256) void row_ptr_kernel(
    const int* __restrict__ dst, int* __restrict__ row_ptr)
{
    int n = blockIdx.x * blockDim.x + threadIdx.x;
    if (n > N_NODES) return;
    int lo = 0, hi = N_EDGES;
    while (lo < hi) {
        int mid = (lo + hi) >> 1;
        if (dst[mid] < n) lo = mid + 1; else hi = mid;
    }
    row_ptr[n] = lo;
}

// Kernel 3: one wave per dst node. Chunk-parallel online softmax:
// 64 lanes each score one edge (coalesced src read, parallel exp),
// wave-reduce max & sum, then gather loop accumulates p * z[s] per dim-lane.
__global__ __launch_bounds__(256) void aggregate_kernel(
    const int* __restrict__ src, const int* __restrict__ row_ptr,
    const float* __restrict__ z, const float* __restrict__ s_src,
    const float* __restrict__ s_dst, float* __restrict__ out)
{
    const int tid  = threadIdx.x;
    const int wave = tid >> 6;
    const int lane = tid & 63;
    const int n = blockIdx.x * 4 + wave;
    if (n >= N_NODES) return;

    const int e0 = row_ptr[n];
    const int e1 = row_ptr[n + 1];
    const float sdn = s_dst[n];

    float m = -INFINITY;
    float denom = 0.f;
    float acc = 0.f;     // this lane's output dim

    for (int c0 = e0; c0 < e1; c0 += 64) {
        const int e = c0 + lane;
        const bool valid = e < e1;
        const int s_l = valid ? src[e] : 0;          // coalesced
        float ev = -INFINITY;
        if (valid) {
            float t = s_src[s_l] + sdn;
            ev = (t > 0.f) ? t : t * NEG_SLOPE;
        }
        // chunk max
        float cm = ev;
#pragma unroll
        for (int off = 32; off; off >>= 1) cm = fmaxf(cm, __shfl_xor(cm, off));
        const float mn = fmaxf(m, cm);
        const float scale = __expf(m - mn);          // first chunk: exp(-inf)=0
        const float p = valid ? __expf(ev - mn) : 0.f;
        float csum = p;
#pragma unroll
        for (int off = 32; off; off >>= 1) csum += __shfl_xor(csum, off);
        denom = denom * scale + csum;
        acc  *= scale;

        const int cnt = (e1 - c0 < 64) ? (e1 - c0) : 64;
        for (int j = 0; j < cnt; ++j) {
            const float pj = __shfl(p, j);
            const int   sj = __shfl(s_l, j);
            acc = fmaf(pj, z[sj * OUT_DIM + lane], acc);  // coalesced 256B gather
        }
        m = mn;
    }
    out[n * OUT_DIM + lane] = (denom > 0.f) ? (acc / denom) : 0.f;
}

extern "C" void kernel_launch(void* const* d_in, const int* in_sizes, int n_in,
                              void* d_out, int out_size, void* d_ws, size_t ws_size,
                              hipStream_t stream)
{
    const float* h      = (const float*)d_in[0];
    const int*   src    = (const int*)  d_in[1];
    const int*   dst    = (const int*)  d_in[2];
    const float* fc_w   = (const float*)d_in[3];
    const float* attn_w = (const float*)d_in[4];
    float*       out    = (float*)d_out;

    char* ws = (char*)d_ws;
    float* z      = (float*)ws;
    ws += ((size_t)N_NODES * OUT_DIM * sizeof(float) + 255) & ~(size_t)255;
    float* s_src  = (float*)ws;
    ws += ((size_t)N_NODES * sizeof(float) + 255) & ~(size_t)255;
    float* s_dst  = (float*)ws;
    ws += ((size_t)N_NODES * sizeof(float) + 255) & ~(size_t)255;
    int* row_ptr  = (int*)ws;
    (void)ws_size;

    const int gemm_blocks = (N_NODES + NPB - 1) / NPB;   // 1563
    gemm_scores_kernel<<<gemm_blocks, 256, 0, stream>>>(h, fc_w, attn_w, z, s_src, s_dst);
    row_ptr_kernel<<<(N_NODES + 1 + 255) / 256, 256, 0, stream>>>(dst, row_ptr);
    aggregate_kernel<<<(N_NODES + 3) / 4, 256, 0, stream>>>(src, row_ptr, z, s_src, s_dst, out);
}

// Round 3
// 102.477 us; speedup vs baseline: 6.9591x; 6.9591x over previous
//
#include <hip/hip_runtime.h>
#include <hip/hip_bf16.h>
#include <math.h>

#define N_NODES 50000
#define N_EDGES 800000
#define IN_DIM 128
#define OUT_DIM 64
#define NEG_SLOPE 0.01f

#define NPW 8            // nodes per wave (gemm)
#define NWAVES 4
#define NPB (NPW * NWAVES)  // 32 nodes per block

// Kernel 1: z = h @ fc_w.T ; also s_src[n]=z[n]·a_src, s_dst[n]=z[n]·a_dst.
// Same conflict-free LDS layout as R2 (measured SQ_LDS_BANK_CONFLICT=0), but
// unroll capped to 2 and VGPRs capped to 3 waves/EU to kill the R2 spills.
__global__ __launch_bounds__(256, 3) void gemm_scores_kernel(
    const float* __restrict__ h, const float* __restrict__ fc_w,
    const float* __restrict__ attn_w,
    float* __restrict__ z, float* __restrict__ s_src, float* __restrict__ s_dst)
{
    __shared__ float wlds[OUT_DIM][IN_DIM + 4];   // 64 x 132 floats = 33 KB
    __shared__ float hlds[NPB][IN_DIM];           // 32 x 128 floats = 16 KB

    const int tid  = threadIdx.x;
    const int wave = tid >> 6;
    const int lane = tid & 63;
    const int n0   = blockIdx.x * NPB;

    // stage fc_w (native layout, float4): 2048 vec4
    for (int idx = tid; idx < OUT_DIM * IN_DIM / 4; idx += 256) {
        int d  = idx >> 5;       // / (IN_DIM/4)
        int kc = idx & 31;
        float4 v = ((const float4*)fc_w)[idx];
        *(float4*)&wlds[d][kc * 4] = v;
    }
    // stage 32 h rows (float4): 1024 vec4
    for (int idx = tid; idx < NPB * IN_DIM / 4; idx += 256) {
        int r  = idx >> 5;
        int kc = idx & 31;
        int n  = n0 + r;
        float4 v = make_float4(0.f, 0.f, 0.f, 0.f);
        if (n < N_NODES) v = ((const float4*)h)[n * (IN_DIM / 4) + kc];
        *(float4*)&hlds[r][kc * 4] = v;
    }
    __syncthreads();

    const int rbase = wave * NPW;
    float acc[NPW];
#pragma unroll
    for (int r = 0; r < NPW; ++r) acc[r] = 0.f;

#pragma unroll 2
    for (int k4 = 0; k4 < IN_DIM / 4; ++k4) {
        const float4 wv = *(const float4*)&wlds[lane][k4 * 4];
#pragma unroll
        for (int r = 0; r < NPW; ++r) {
            const float4 hv = *(const float4*)&hlds[rbase + r][k4 * 4]; // uniform → broadcast
            acc[r] = fmaf(wv.x, hv.x, acc[r]);
            acc[r] = fmaf(wv.y, hv.y, acc[r]);
            acc[r] = fmaf(wv.z, hv.z, acc[r]);
            acc[r] = fmaf(wv.w, hv.w, acc[r]);
        }
    }

    const float asrc = attn_w[lane];
    const float adst = attn_w[OUT_DIM + lane];

#pragma unroll
    for (int r = 0; r < NPW; ++r) {
        const int n = n0 + rbase + r;
        if (n < N_NODES) {                  // wave-uniform branch
            z[n * OUT_DIM + lane] = acc[r];
            float ps = acc[r] * asrc;
            float pd = acc[r] * adst;
#pragma unroll
            for (int off = 32; off; off >>= 1) {
                ps += __shfl_xor(ps, off);
                pd += __shfl_xor(pd, off);
            }
            if (lane == 0) { s_src[n] = ps; s_dst[n] = pd; }
        }
    }
}

// Kernel 2: row_ptr[n] = lower_bound(dst, n)  (dst is sorted)
__global__ __launch_bounds__(256) void row_ptr_kernel(
    const int* __restrict__ dst, int* __restrict__ row_ptr)
{
    int n = blockIdx.x * blockDim.x + threadIdx.x;
    if (n > N_NODES) return;
    int lo = 0, hi = N_EDGES;
    while (lo < hi) {
        int mid = (lo + hi) >> 1;
        if (dst[mid] < n) lo = mid + 1; else hi = mid;
    }
    row_ptr[n] = lo;
}

// Kernel 3: one wave per dst node. Chunk-parallel online softmax:
// 64 lanes each score one edge (coalesced src read, parallel exp),
// wave-reduce max & sum, then gather loop accumulates p * z[s] per dim-lane.
__global__ __launch_bounds__(256) void aggregate_kernel(
    const int* __restrict__ src, const int* __restrict__ row_ptr,
    const float* __restrict__ z, const float* __restrict__ s_src,
    const float* __restrict__ s_dst, float* __restrict__ out)
{
    const int tid  = threadIdx.x;
    const int wave = tid >> 6;
    const int lane = tid & 63;
    const int n = blockIdx.x * 4 + wave;
    if (n >= N_NODES) return;

    const int e0 = row_ptr[n];
    const int e1 = row_ptr[n + 1];
    const float sdn = s_dst[n];

    float m = -INFINITY;
    float denom = 0.f;
    float acc = 0.f;     // this lane's output dim

    for (int c0 = e0; c0 < e1; c0 += 64) {
        const int e = c0 + lane;
        const bool valid = e < e1;
        const int s_l = valid ? src[e] : 0;          // coalesced
        float ev = -INFINITY;
        if (valid) {
            float t = s_src[s_l] + sdn;
            ev = (t > 0.f) ? t : t * NEG_SLOPE;
        }
        // chunk max
        float cm = ev;
#pragma unroll
        for (int off = 32; off; off >>= 1) cm = fmaxf(cm, __shfl_xor(cm, off));
        const float mn = fmaxf(m, cm);
        const float scale = __expf(m - mn);          // first chunk: exp(-inf)=0
        const float p = valid ? __expf(ev - mn) : 0.f;
        float csum = p;
#pragma unroll
        for (int off = 32; off; off >>= 1) csum += __shfl_xor(csum, off);
        denom = denom * scale + csum;
        acc  *= scale;

        const int cnt = (e1 - c0 < 64) ? (e1 - c0) : 64;
        for (int j = 0; j < cnt; ++j) {
            const float pj = __shfl(p, j);
            const int   sj = __shfl(s_l, j);
            acc = fmaf(pj, z[sj * OUT_DIM + lane], acc);  // coalesced 256B gather
        }
        m = mn;
    }
    out[n * OUT_DIM + lane] = (denom > 0.f) ? (acc / denom) : 0.f;
}

extern "C" void kernel_launch(void* const* d_in, const int* in_sizes, int n_in,
                              void* d_out, int out_size, void* d_ws, size_t ws_size,
                              hipStream_t stream)
{
    const float* h      = (const float*)d_in[0];
    const int*   src    = (const int*)  d_in[1];
    const int*   dst    = (const int*)  d_in[2];
    const float* fc_w   = (const float*)d_in[3];
    const float* attn_w = (const float*)d_in[4];
    float*       out    = (float*)d_out;

    char* ws = (char*)d_ws;
    float* z      = (float*)ws;
    ws += ((size_t)N_NODES * OUT_DIM * sizeof(float) + 255) & ~(size_t)255;
    float* s_src  = (float*)ws;
    ws += ((size_t)N_NODES * sizeof(float) + 255) & ~(size_t)255;
    float* s_dst  = (float*)ws;
    ws += ((size_t)N_NODES * sizeof(float) + 255) & ~(size_t)255;
    int* row_ptr  = (int*)ws;
    (void)ws_size;

    const int gemm_blocks = (N_NODES + NPB - 1) / NPB;   // 1563
    gemm_scores_kernel<<<gemm_blocks, 256, 0, stream>>>(h, fc_w, attn_w, z, s_src, s_dst);
    row_ptr_kernel<<<(N_NODES + 1 + 255) / 256, 256, 0, stream>>>(dst, row_ptr);
    aggregate_kernel<<<(N_NODES + 3) / 4, 256, 0, stream>>>(src, row_ptr, z, s_src, s_dst, out);
}

// Round 4
// 96.772 us; speedup vs baseline: 7.3693x; 1.0589x over previous
//
#include <hip/hip_runtime.h>
#include <hip/hip_bf16.h>
#include <math.h>

#define N_NODES 50000
#define N_EDGES 800000
#define IN_DIM 128
#define OUT_DIM 64
#define NEG_SLOPE 0.01f

#define NPW 8            // nodes per wave (gemm)
#define NWAVES 4
#define NPB (NPW * NWAVES)  // 32 nodes per block

// Kernel 1: z = h @ fc_w.T ; also s_src[n]=z[n]·a_src, s_dst[n]=z[n]·a_dst.
// Weights (shared by all waves) staged in LDS, conflict-free padded layout.
// h rows are consumed by exactly one wave -> read straight from global with a
// wave-uniform base (readfirstlane) so the compiler can use scalar/broadcast
// loads; no LDS round-trip for h (R3 was LDS-pipe bound on those reads).
__global__ __launch_bounds__(256, 4) void gemm_scores_kernel(
    const float* __restrict__ h, const float* __restrict__ fc_w,
    const float* __restrict__ attn_w,
    float* __restrict__ z, float* __restrict__ s_src, float* __restrict__ s_dst)
{
    __shared__ float wlds[OUT_DIM][IN_DIM + 4];   // 64 x 132 floats = 33 KB

    const int tid  = threadIdx.x;
    const int wave = tid >> 6;
    const int lane = tid & 63;
    const int n0   = blockIdx.x * NPB;

    // stage fc_w (native layout, float4): 2048 vec4, conflict-free
    for (int idx = tid; idx < OUT_DIM * IN_DIM / 4; idx += 256) {
        int d  = idx >> 5;       // / (IN_DIM/4)
        int kc = idx & 31;
        float4 v = ((const float4*)fc_w)[idx];
        *(float4*)&wlds[d][kc * 4] = v;
    }
    __syncthreads();

    // wave-uniform node base (forced into SGPR)
    const int rbase = __builtin_amdgcn_readfirstlane(n0 + wave * NPW);

    const float4* hp[NPW];
#pragma unroll
    for (int r = 0; r < NPW; ++r) {
        int n = rbase + r;
        if (n > N_NODES - 1) n = N_NODES - 1;   // clamp for safe loads
        hp[r] = (const float4*)(h + (size_t)n * IN_DIM);
    }

    float acc[NPW];
#pragma unroll
    for (int r = 0; r < NPW; ++r) acc[r] = 0.f;

#pragma unroll 4
    for (int k4 = 0; k4 < IN_DIM / 4; ++k4) {
        const float4 wv = *(const float4*)&wlds[lane][k4 * 4];
#pragma unroll
        for (int r = 0; r < NPW; ++r) {
            const float4 hv = hp[r][k4];        // wave-uniform -> broadcast
            acc[r] = fmaf(wv.x, hv.x, acc[r]);
            acc[r] = fmaf(wv.y, hv.y, acc[r]);
            acc[r] = fmaf(wv.z, hv.z, acc[r]);
            acc[r] = fmaf(wv.w, hv.w, acc[r]);
        }
    }

    const float asrc = attn_w[lane];
    const float adst = attn_w[OUT_DIM + lane];

#pragma unroll
    for (int r = 0; r < NPW; ++r) {
        const int n = rbase + r;
        if (n < N_NODES) {                  // wave-uniform branch
            z[(size_t)n * OUT_DIM + lane] = acc[r];
            float ps = acc[r] * asrc;
            float pd = acc[r] * adst;
#pragma unroll
            for (int off = 32; off; off >>= 1) {
                ps += __shfl_xor(ps, off);
                pd += __shfl_xor(pd, off);
            }
            if (lane == 0) { s_src[n] = ps; s_dst[n] = pd; }
        }
    }
}

// Kernel 2: row_ptr[n] = lower_bound(dst, n)  (dst is sorted)
__global__ __launch_bounds__(256) void row_ptr_kernel(
    const int* __restrict__ dst, int* __restrict__ row_ptr)
{
    int n = blockIdx.x * blockDim.x + threadIdx.x;
    if (n > N_NODES) return;
    int lo = 0, hi = N_EDGES;
    while (lo < hi) {
        int mid = (lo + hi) >> 1;
        if (dst[mid] < n) lo = mid + 1; else hi = mid;
    }
    row_ptr[n] = lo;
}

// Kernel 3: one wave per dst node, lane = output dim. Chunk-parallel online
// softmax; gather loop unrolled x4 with independent partial accumulators so
// 4 z-row loads are in flight per wave (R3 was latency-bound at 1).
__global__ __launch_bounds__(256) void aggregate_kernel(
    const int* __restrict__ src, const int* __restrict__ row_ptr,
    const float* __restrict__ z, const float* __restrict__ s_src,
    const float* __restrict__ s_dst, float* __restrict__ out)
{
    const int tid  = threadIdx.x;
    const int wave = tid >> 6;
    const int lane = tid & 63;
    const int n = blockIdx.x * 4 + wave;
    if (n >= N_NODES) return;

    const int e0 = row_ptr[n];
    const int e1 = row_ptr[n + 1];
    const float sdn = s_dst[n];

    float m = -INFINITY;
    float denom = 0.f;
    float acc = 0.f;     // this lane's output dim

    for (int c0 = e0; c0 < e1; c0 += 64) {
        const int e = c0 + lane;
        const bool valid = e < e1;
        const int s_l = valid ? src[e] : 0;          // coalesced
        float ev = -INFINITY;
        if (valid) {
            float t = s_src[s_l] + sdn;
            ev = (t > 0.f) ? t : t * NEG_SLOPE;
        }
        // chunk max
        float cm = ev;
#pragma unroll
        for (int off = 32; off; off >>= 1) cm = fmaxf(cm, __shfl_xor(cm, off));
        const float mn = fmaxf(m, cm);
        const float scale = __expf(m - mn);          // first chunk: exp(-inf)=0
        const float p = valid ? __expf(ev - mn) : 0.f;
        float csum = p;
#pragma unroll
        for (int off = 32; off; off >>= 1) csum += __shfl_xor(csum, off);

        const int cnt = (e1 - c0 < 64) ? (e1 - c0) : 64;
        float a0 = 0.f, a1 = 0.f, a2 = 0.f, a3 = 0.f;
        int j = 0;
        for (; j + 4 <= cnt; j += 4) {
            const float p0 = __shfl(p, j + 0); const int s0 = __shfl(s_l, j + 0);
            const float p1 = __shfl(p, j + 1); const int s1 = __shfl(s_l, j + 1);
            const float p2 = __shfl(p, j + 2); const int s2 = __shfl(s_l, j + 2);
            const float p3 = __shfl(p, j + 3); const int s3 = __shfl(s_l, j + 3);
            a0 = fmaf(p0, z[(size_t)s0 * OUT_DIM + lane], a0);
            a1 = fmaf(p1, z[(size_t)s1 * OUT_DIM + lane], a1);
            a2 = fmaf(p2, z[(size_t)s2 * OUT_DIM + lane], a2);
            a3 = fmaf(p3, z[(size_t)s3 * OUT_DIM + lane], a3);
        }
        for (; j < cnt; ++j) {
            const float pj = __shfl(p, j);
            const int   sj = __shfl(s_l, j);
            a0 = fmaf(pj, z[(size_t)sj * OUT_DIM + lane], a0);
        }
        denom = denom * scale + csum;
        acc   = acc * scale + ((a0 + a1) + (a2 + a3));
        m = mn;
    }
    out[(size_t)n * OUT_DIM + lane] = (denom > 0.f) ? (acc / denom) : 0.f;
}

extern "C" void kernel_launch(void* const* d_in, const int* in_sizes, int n_in,
                              void* d_out, int out_size, void* d_ws, size_t ws_size,
                              hipStream_t stream)
{
    const float* h      = (const float*)d_in[0];
    const int*   src    = (const int*)  d_in[1];
    const int*   dst    = (const int*)  d_in[2];
    const float* fc_w   = (const float*)d_in[3];
    const float* attn_w = (const float*)d_in[4];
    float*       out    = (float*)d_out;

    char* ws = (char*)d_ws;
    float* z      = (float*)ws;
    ws += ((size_t)N_NODES * OUT_DIM * sizeof(float) + 255) & ~(size_t)255;
    float* s_src  = (float*)ws;
    ws += ((size_t)N_NODES * sizeof(float) + 255) & ~(size_t)255;
    float* s_dst  = (float*)ws;
    ws += ((size_t)N_NODES * sizeof(float) + 255) & ~(size_t)255;
    int* row_ptr  = (int*)ws;
    (void)ws_size;

    const int gemm_blocks = (N_NODES + NPB - 1) / NPB;   // 1563
    row_ptr_kernel<<<(N_NODES + 1 + 255) / 256, 256, 0, stream>>>(dst, row_ptr);
    gemm_scores_kernel<<<gemm_blocks, 256, 0, stream>>>(h, fc_w, attn_w, z, s_src, s_dst);
    aggregate_kernel<<<(N_NODES + 3) / 4, 256, 0, stream>>>(src, row_ptr, z, s_src, s_dst, out);
}

// Round 5
// 60.068 us; speedup vs baseline: 11.8723x; 1.6110x over previous
//
#include <hip/hip_runtime.h>
#include <hip/hip_bf16.h>
#include <math.h>

#define N_NODES 50000
#define N_EDGES 800000
#define IN_DIM 128
#define OUT_DIM 64
#define NEG_SLOPE 0.01f

typedef unsigned short u16;
typedef unsigned int   u32;
typedef __attribute__((ext_vector_type(8))) short bf16x8_t;
typedef __attribute__((ext_vector_type(4))) float f32x4_t;

static __device__ __forceinline__ u16 f2bf(float x) {
    u32 u = __float_as_uint(x);
    u = (u + 0x7fffu + ((u >> 16) & 1u)) >> 16;   // round-to-nearest-even
    return (u16)u;
}
static __device__ __forceinline__ float bf2f(u16 b) {
    return __uint_as_float(((u32)b) << 16);
}

// Kernel 1 (prep): row_ptr[n] = lower_bound(dst, n); also fc_w -> bf16.
__global__ __launch_bounds__(256) void prep_kernel(
    const int* __restrict__ dst, const float* __restrict__ fc_w,
    int* __restrict__ row_ptr, u16* __restrict__ wbf)
{
    const int t = blockIdx.x * blockDim.x + threadIdx.x;
    if (t < OUT_DIM * IN_DIM) wbf[t] = f2bf(fc_w[t]);
    if (t > N_NODES) return;
    int lo = 0, hi = N_EDGES;
    while (lo < hi) {
        int mid = (lo + hi) >> 1;
        if (dst[mid] < t) lo = mid + 1; else hi = mid;
    }
    row_ptr[t] = lo;
}

// Kernel 2: z = h @ fc_w.T via bf16 MFMA; z stored bf16; s_src/s_dst f32.
// One wave = 16 nodes x 64 dims, no LDS.
// A-frag: lane l holds h[n0+(l&15)][32*kc + 8*(l>>4) + j], j=0..7.
// B-frag: lane l holds w[dt*16+(l&15)][32*kc + 8*(l>>4) + j]  (bf16 copy).
// D (m89-verified): col = lane&15, row = 4*(lane>>4) + reg.
__global__ __launch_bounds__(256) void gemm_mfma_kernel(
    const float* __restrict__ h, const u16* __restrict__ wbf,
    const float* __restrict__ attn_w,
    u16* __restrict__ zb, float* __restrict__ s_src, float* __restrict__ s_dst)
{
    const int tid  = threadIdx.x;
    const int wid  = blockIdx.x * 4 + (tid >> 6);
    if (wid >= N_NODES / 16) return;               // 3125 waves exactly
    const int lane = tid & 63;
    const int row  = lane & 15;
    const int kq   = lane >> 4;
    const int n0   = wid * 16;

    bf16x8_t afr[4];
    const float* hrow = h + (size_t)(n0 + row) * IN_DIM + 8 * kq;
#pragma unroll
    for (int kc = 0; kc < 4; ++kc) {
        const float4 f0 = *(const float4*)(hrow + 32 * kc);
        const float4 f1 = *(const float4*)(hrow + 32 * kc + 4);
        bf16x8_t a;
        a[0] = (short)f2bf(f0.x); a[1] = (short)f2bf(f0.y);
        a[2] = (short)f2bf(f0.z); a[3] = (short)f2bf(f0.w);
        a[4] = (short)f2bf(f1.x); a[5] = (short)f2bf(f1.y);
        a[6] = (short)f2bf(f1.z); a[7] = (short)f2bf(f1.w);
        afr[kc] = a;
    }

    f32x4_t acc[4];
#pragma unroll
    for (int dt = 0; dt < 4; ++dt) {
        f32x4_t c = {0.f, 0.f, 0.f, 0.f};
#pragma unroll
        for (int kc = 0; kc < 4; ++kc) {
            const bf16x8_t bfr =
                *(const bf16x8_t*)(wbf + (size_t)(dt * 16 + row) * IN_DIM + 32 * kc + 8 * kq);
            c = __builtin_amdgcn_mfma_f32_16x16x32_bf16(afr[kc], bfr, c, 0, 0, 0);
        }
        acc[dt] = c;
    }

#pragma unroll
    for (int dt = 0; dt < 4; ++dt)
#pragma unroll
        for (int r = 0; r < 4; ++r)
            zb[(size_t)(n0 + 4 * kq + r) * OUT_DIM + dt * 16 + row] = f2bf(acc[dt][r]);

    float a_s[4], a_d[4];
#pragma unroll
    for (int dt = 0; dt < 4; ++dt) {
        a_s[dt] = attn_w[dt * 16 + row];
        a_d[dt] = attn_w[OUT_DIM + dt * 16 + row];
    }
#pragma unroll
    for (int r = 0; r < 4; ++r) {
        float ps = 0.f, pd = 0.f;
#pragma unroll
        for (int dt = 0; dt < 4; ++dt) {
            ps = fmaf(acc[dt][r], a_s[dt], ps);
            pd = fmaf(acc[dt][r], a_d[dt], pd);
        }
#pragma unroll
        for (int m = 1; m < 16; m <<= 1) {
            ps += __shfl_xor(ps, m);
            pd += __shfl_xor(pd, m);
        }
        if (row == 0) {
            const int n = n0 + 4 * kq + r;
            s_src[n] = ps;
            s_dst[n] = pd;
        }
    }
}

// Kernel 3: one wave per dst node, lane = output dim. Chunk-parallel online
// softmax; bf16 z gather (128B rows), unrolled x8.
__global__ __launch_bounds__(256) void aggregate_kernel(
    const int* __restrict__ src, const int* __restrict__ row_ptr,
    const u16* __restrict__ zb, const float* __restrict__ s_src,
    const float* __restrict__ s_dst, float* __restrict__ out)
{
    const int tid  = threadIdx.x;
    const int wave = tid >> 6;
    const int lane = tid & 63;
    const int n = blockIdx.x * 4 + wave;
    if (n >= N_NODES) return;

    const int e0 = row_ptr[n];
    const int e1 = row_ptr[n + 1];
    const float sdn = s_dst[n];

    float m = -INFINITY;
    float denom = 0.f;
    float acc = 0.f;

    for (int c0 = e0; c0 < e1; c0 += 64) {
        const int e = c0 + lane;
        const bool valid = e < e1;
        const int s_l = valid ? src[e] : 0;
        float ev = -INFINITY;
        if (valid) {
            float t = s_src[s_l] + sdn;
            ev = (t > 0.f) ? t : t * NEG_SLOPE;
        }
        float cm = ev;
#pragma unroll
        for (int off = 32; off; off >>= 1) cm = fmaxf(cm, __shfl_xor(cm, off));
        const float mn = fmaxf(m, cm);
        const float scale = __expf(m - mn);
        const float p = valid ? __expf(ev - mn) : 0.f;
        float csum = p;
#pragma unroll
        for (int off = 32; off; off >>= 1) csum += __shfl_xor(csum, off);

        const int cnt = (e1 - c0 < 64) ? (e1 - c0) : 64;
        float a0 = 0.f, a1 = 0.f, a2 = 0.f, a3 = 0.f;
        float a4 = 0.f, a5 = 0.f, a6 = 0.f, a7 = 0.f;
        int j = 0;
        for (; j + 8 <= cnt; j += 8) {
            const float p0 = __shfl(p, j+0); const int s0 = __shfl(s_l, j+0);
            const float p1 = __shfl(p, j+1); const int s1 = __shfl(s_l, j+1);
            const float p2 = __shfl(p, j+2); const int s2 = __shfl(s_l, j+2);
            const float p3 = __shfl(p, j+3); const int s3 = __shfl(s_l, j+3);
            const float p4 = __shfl(p, j+4); const int s4 = __shfl(s_l, j+4);
            const float p5 = __shfl(p, j+5); const int s5 = __shfl(s_l, j+5);
            const float p6 = __shfl(p, j+6); const int s6 = __shfl(s_l, j+6);
            const float p7 = __shfl(p, j+7); const int s7 = __shfl(s_l, j+7);
            a0 = fmaf(p0, bf2f(zb[(size_t)s0 * OUT_DIM + lane]), a0);
            a1 = fmaf(p1, bf2f(zb[(size_t)s1 * OUT_DIM + lane]), a1);
            a2 = fmaf(p2, bf2f(zb[(size_t)s2 * OUT_DIM + lane]), a2);
            a3 = fmaf(p3, bf2f(zb[(size_t)s3 * OUT_DIM + lane]), a3);
            a4 = fmaf(p4, bf2f(zb[(size_t)s4 * OUT_DIM + lane]), a4);
            a5 = fmaf(p5, bf2f(zb[(size_t)s5 * OUT_DIM + lane]), a5);
            a6 = fmaf(p6, bf2f(zb[(size_t)s6 * OUT_DIM + lane]), a6);
            a7 = fmaf(p7, bf2f(zb[(size_t)s7 * OUT_DIM + lane]), a7);
        }
        for (; j < cnt; ++j) {
            const float pj = __shfl(p, j);
            const int   sj = __shfl(s_l, j);
            a0 = fmaf(pj, bf2f(zb[(size_t)sj * OUT_DIM + lane]), a0);
        }
        denom = denom * scale + csum;
        acc   = acc * scale + (((a0 + a1) + (a2 + a3)) + ((a4 + a5) + (a6 + a7)));
        m = mn;
    }
    out[(size_t)n * OUT_DIM + lane] = (denom > 0.f) ? (acc / denom) : 0.f;
}

extern "C" void kernel_launch(void* const* d_in, const int* in_sizes, int n_in,
                              void* d_out, int out_size, void* d_ws, size_t ws_size,
                              hipStream_t stream)
{
    const float* h      = (const float*)d_in[0];
    const int*   src    = (const int*)  d_in[1];
    const int*   dst    = (const int*)  d_in[2];
    const float* fc_w   = (const float*)d_in[3];
    const float* attn_w = (const float*)d_in[4];
    float*       out    = (float*)d_out;

    char* ws = (char*)d_ws;
    u16* zb = (u16*)ws;                                           // 6.4 MB
    ws += ((size_t)N_NODES * OUT_DIM * sizeof(u16) + 255) & ~(size_t)255;
    float* s_src = (float*)ws;
    ws += ((size_t)N_NODES * sizeof(float) + 255) & ~(size_t)255;
    float* s_dst = (float*)ws;
    ws += ((size_t)N_NODES * sizeof(float) + 255) & ~(size_t)255;
    int* row_ptr = (int*)ws;
    ws += ((size_t)(N_NODES + 1) * sizeof(int) + 255) & ~(size_t)255;
    u16* wbf = (u16*)ws;                                          // 16 KB
    (void)ws_size;

    prep_kernel<<<(N_NODES + 1 + 255) / 256, 256, 0, stream>>>(dst, fc_w, row_ptr, wbf);
    const int gemm_blocks = (N_NODES / 16 + 3) / 4;               // 782
    gemm_mfma_kernel<<<gemm_blocks, 256, 0, stream>>>(h, wbf, attn_w, zb, s_src, s_dst);
    aggregate_kernel<<<(N_NODES + 3) / 4, 256, 0, stream>>>(src, row_ptr, zb, s_src, s_dst, out);
}

// Round 6
// 46.845 us; speedup vs baseline: 15.2233x; 1.2823x over previous
//
#include <hip/hip_runtime.h>
#include <hip/hip_bf16.h>
#include <math.h>

#define N_NODES 50000
#define N_EDGES 800000
#define IN_DIM 128
#define OUT_DIM 64
#define NEG_SLOPE 0.01f

typedef unsigned short u16;
typedef unsigned int   u32;
typedef __attribute__((ext_vector_type(8))) short bf16x8_t;
typedef __attribute__((ext_vector_type(4))) float f32x4_t;

static __device__ __forceinline__ u16 f2bf(float x) {
    u32 u = __float_as_uint(x);
    u = (u + 0x7fffu + ((u >> 16) & 1u)) >> 16;   // round-to-nearest-even
    return (u16)u;
}

// Kernel A (fused): fc_w -> bf16 staged in LDS (pad +8 u16 -> optimal b128
// reads), z = h @ fc_w.T via MFMA (one wave = 16 nodes), s_src/s_dst
// epilogue, and row_ptr lower_bound as kernel tail (latency hides under
// co-resident waves' MFMA work; gemm is neither BW- nor issue-bound).
__global__ __launch_bounds__(256) void gemm_fused_kernel(
    const float* __restrict__ h, const float* __restrict__ fc_w,
    const float* __restrict__ attn_w, const int* __restrict__ dst,
    u16* __restrict__ zb, float* __restrict__ s_src, float* __restrict__ s_dst,
    int* __restrict__ row_ptr)
{
    __shared__ u16 wlds[OUT_DIM][IN_DIM + 8];   // 64 x 136 u16 = 17.4 KB

    const int tid  = threadIdx.x;
    const int lane = tid & 63;
    const int wid  = blockIdx.x * 4 + (tid >> 6);
    const int row  = lane & 15;
    const int kq   = lane >> 4;

    // stage + convert fc_w: float2 -> packed 2x bf16 (u32 writes, 2-way=free)
    for (int idx = tid; idx < OUT_DIM * IN_DIM / 2; idx += 256) {
        const int d  = idx >> 6;           // / (IN_DIM/2)
        const int kk = idx & 63;
        const float2 f = ((const float2*)fc_w)[idx];
        const u32 w = ((u32)f2bf(f.y) << 16) | (u32)f2bf(f.x);
        *(u32*)&wlds[d][2 * kk] = w;
    }
    __syncthreads();

    if (wid < N_NODES / 16) {              // 3125 waves exactly
        const int n0 = wid * 16;

        // A-frags: lane holds h[n0+row][32*kc + 8*kq + j], j=0..7 (f32->bf16)
        bf16x8_t afr[4];
        const float* hrow = h + (size_t)(n0 + row) * IN_DIM + 8 * kq;
#pragma unroll
        for (int kc = 0; kc < 4; ++kc) {
            const float4 f0 = *(const float4*)(hrow + 32 * kc);
            const float4 f1 = *(const float4*)(hrow + 32 * kc + 4);
            bf16x8_t a;
            a[0] = (short)f2bf(f0.x); a[1] = (short)f2bf(f0.y);
            a[2] = (short)f2bf(f0.z); a[3] = (short)f2bf(f0.w);
            a[4] = (short)f2bf(f1.x); a[5] = (short)f2bf(f1.y);
            a[6] = (short)f2bf(f1.z); a[7] = (short)f2bf(f1.w);
            afr[kc] = a;
        }

        f32x4_t acc[4];
#pragma unroll
        for (int dt = 0; dt < 4; ++dt) {
            f32x4_t c = {0.f, 0.f, 0.f, 0.f};
#pragma unroll
            for (int kc = 0; kc < 4; ++kc) {
                const bf16x8_t bfr =
                    *(const bf16x8_t*)&wlds[dt * 16 + row][32 * kc + 8 * kq];
                c = __builtin_amdgcn_mfma_f32_16x16x32_bf16(afr[kc], bfr, c, 0, 0, 0);
            }
            acc[dt] = c;
        }

        // store z (bf16). D layout (m89): col = lane&15, row = 4*(lane>>4)+reg
#pragma unroll
        for (int dt = 0; dt < 4; ++dt)
#pragma unroll
            for (int r = 0; r < 4; ++r)
                zb[(size_t)(n0 + 4 * kq + r) * OUT_DIM + dt * 16 + row] = f2bf(acc[dt][r]);

        // attention scores: reduce over 4 dim-tiles x 16 lanes
        float a_s[4], a_d[4];
#pragma unroll
        for (int dt = 0; dt < 4; ++dt) {
            a_s[dt] = attn_w[dt * 16 + row];
            a_d[dt] = attn_w[OUT_DIM + dt * 16 + row];
        }
#pragma unroll
        for (int r = 0; r < 4; ++r) {
            float ps = 0.f, pd = 0.f;
#pragma unroll
            for (int dt = 0; dt < 4; ++dt) {
                ps = fmaf(acc[dt][r], a_s[dt], ps);
                pd = fmaf(acc[dt][r], a_d[dt], pd);
            }
#pragma unroll
            for (int mm = 1; mm < 16; mm <<= 1) {
                ps += __shfl_xor(ps, mm);
                pd += __shfl_xor(pd, mm);
            }
            if (row == 0) {
                const int n = n0 + 4 * kq + r;
                s_src[n] = ps;
                s_dst[n] = pd;
            }
        }
    }

    // ---- kernel tail: row_ptr[gt] = lower_bound(dst, gt) ----
    const int gt = blockIdx.x * 256 + tid;
    if (gt <= N_NODES) {
        int lo = 0, hi = N_EDGES;
        while (lo < hi) {
            const int mid = (lo + hi) >> 1;
            if (dst[mid] < gt) lo = mid + 1; else hi = mid;
        }
        row_ptr[gt] = lo;
    }
}

// Kernel B: one wave per dst node. Chunk-parallel online softmax.
// Gather phase: lane halves split even/odd edges, each lane reads u32 = 2 bf16
// dims -> 2 edges (256B) per instruction, 4 pair-loads in flight.
__global__ __launch_bounds__(256) void aggregate_kernel(
    const int* __restrict__ src, const int* __restrict__ row_ptr,
    const u16* __restrict__ zb, const float* __restrict__ s_src,
    const float* __restrict__ s_dst, float* __restrict__ out)
{
    const int tid  = threadIdx.x;
    const int lane = tid & 63;
    const int n = blockIdx.x * 4 + (tid >> 6);
    if (n >= N_NODES) return;
    const int sub = lane & 31;    // dim pair index (dims 2*sub, 2*sub+1)
    const int pr  = lane >> 5;    // edge parity half

    const int e0 = row_ptr[n];
    const int e1 = row_ptr[n + 1];
    const float sdn = s_dst[n];

    float m = -INFINITY;
    float denom = 0.f;
    float accA = 0.f, accB = 0.f;

    for (int c0 = e0; c0 < e1; c0 += 64) {
        const int e = c0 + lane;
        const bool valid = e < e1;
        const int s_l = valid ? src[e] : 0;            // coalesced
        float ev = -INFINITY;
        if (valid) {
            float t = s_src[s_l] + sdn;
            ev = (t > 0.f) ? t : t * NEG_SLOPE;
        }
        float cm = ev;
#pragma unroll
        for (int off = 32; off; off >>= 1) cm = fmaxf(cm, __shfl_xor(cm, off));
        const float mn = fmaxf(m, cm);
        const float scale = __expf(m - mn);            // first chunk: 0
        const float p = valid ? __expf(ev - mn) : 0.f;
        float csum = p;
#pragma unroll
        for (int off = 32; off; off >>= 1) csum += __shfl_xor(csum, off);

        const int cnt = (e1 - c0 < 64) ? (e1 - c0) : 64;
        float aA[4] = {0.f, 0.f, 0.f, 0.f};
        float aB[4] = {0.f, 0.f, 0.f, 0.f};
        int j = 0;
        for (; j + 8 <= cnt; j += 8) {
#pragma unroll
            for (int u = 0; u < 4; ++u) {
                const int jj = j + 2 * u + pr;
                const float pj = __shfl(p, jj);
                const int   sj = __shfl(s_l, jj);
                const u32 w = *(const u32*)(zb + (size_t)sj * OUT_DIM + 2 * sub);
                aA[u] = fmaf(pj, __uint_as_float(w << 16), aA[u]);
                aB[u] = fmaf(pj, __uint_as_float(w & 0xffff0000u), aB[u]);
            }
        }
        for (; j < cnt; j += 2) {
            const int jj = j + pr;
            const float pj = __shfl(p, jj);
            const int   sj = __shfl(s_l, jj);
            if (jj < cnt) {
                const u32 w = *(const u32*)(zb + (size_t)sj * OUT_DIM + 2 * sub);
                aA[0] = fmaf(pj, __uint_as_float(w << 16), aA[0]);
                aB[0] = fmaf(pj, __uint_as_float(w & 0xffff0000u), aB[0]);
            }
        }
        denom = denom * scale + csum;
        accA  = accA * scale + ((aA[0] + aA[1]) + (aA[2] + aA[3]));
        accB  = accB * scale + ((aB[0] + aB[1]) + (aB[2] + aB[3]));
        m = mn;
    }

    // combine even/odd edge halves (same dims, different edge subsets)
    accA += __shfl_xor(accA, 32);
    accB += __shfl_xor(accB, 32);
    if (pr == 0) {
        const float inv = (denom > 0.f) ? (1.f / denom) : 0.f;
        float2 o = make_float2(accA * inv, accB * inv);
        *(float2*)(out + (size_t)n * OUT_DIM + 2 * sub) = o;   // 256B/wave
    }
}

extern "C" void kernel_launch(void* const* d_in, const int* in_sizes, int n_in,
                              void* d_out, int out_size, void* d_ws, size_t ws_size,
                              hipStream_t stream)
{
    const float* h      = (const float*)d_in[0];
    const int*   src    = (const int*)  d_in[1];
    const int*   dst    = (const int*)  d_in[2];
    const float* fc_w   = (const float*)d_in[3];
    const float* attn_w = (const float*)d_in[4];
    float*       out    = (float*)d_out;

    char* ws = (char*)d_ws;
    u16* zb = (u16*)ws;                                           // 6.4 MB
    ws += ((size_t)N_NODES * OUT_DIM * sizeof(u16) + 255) & ~(size_t)255;
    float* s_src = (float*)ws;
    ws += ((size_t)N_NODES * sizeof(float) + 255) & ~(size_t)255;
    float* s_dst = (float*)ws;
    ws += ((size_t)N_NODES * sizeof(float) + 255) & ~(size_t)255;
    int* row_ptr = (int*)ws;
    (void)ws_size;

    const int gemm_blocks = (N_NODES / 16 + 3) / 4;               // 782
    gemm_fused_kernel<<<gemm_blocks, 256, 0, stream>>>(
        h, fc_w, attn_w, dst, zb, s_src, s_dst, row_ptr);
    aggregate_kernel<<<(N_NODES + 3) / 4, 256, 0, stream>>>(
        src, row_ptr, zb, s_src, s_dst, out);
}

// Round 7
// 45.313 us; speedup vs baseline: 15.7382x; 1.0338x over previous
//
#include <hip/hip_runtime.h>
#include <hip/hip_bf16.h>
#include <math.h>

#define N_NODES 50000
#define N_EDGES 800000
#define IN_DIM 128
#define OUT_DIM 64
#define NEG_SLOPE 0.01f

typedef unsigned short u16;
typedef unsigned int   u32;
typedef __attribute__((ext_vector_type(8))) short bf16x8_t;
typedef __attribute__((ext_vector_type(4))) float f32x4_t;

static __device__ __forceinline__ u16 f2bf(float x) {
    __hip_bfloat16 b = __float2bfloat16(x);      // hardware cvt (RNE on gfx950)
    return __builtin_bit_cast(u16, b);
}
static __device__ __forceinline__ float bflo(u32 w) { return __uint_as_float(w << 16); }
static __device__ __forceinline__ float bfhi(u32 w) { return __uint_as_float(w & 0xffff0000u); }

// Kernel A (fused): fc_w -> bf16 in LDS (pad +8 -> conflict-free b128 reads),
// z = h @ fc_w.T via MFMA (one wave = 16 nodes), s_src/s_dst epilogue, and
// row_ptr lower_bound as kernel tail (hides under co-resident MFMA waves).
__global__ __launch_bounds__(256) void gemm_fused_kernel(
    const float* __restrict__ h, const float* __restrict__ fc_w,
    const float* __restrict__ attn_w, const int* __restrict__ dst,
    u16* __restrict__ zb, float* __restrict__ s_src, float* __restrict__ s_dst,
    int* __restrict__ row_ptr)
{
    __shared__ u16 wlds[OUT_DIM][IN_DIM + 8];   // 64 x 136 u16 = 17.4 KB

    const int tid  = threadIdx.x;
    const int lane = tid & 63;
    const int wid  = blockIdx.x * 4 + (tid >> 6);
    const int row  = lane & 15;
    const int kq   = lane >> 4;

    // stage + convert fc_w: float2 -> packed 2x bf16 (u32 writes)
    for (int idx = tid; idx < OUT_DIM * IN_DIM / 2; idx += 256) {
        const int d  = idx >> 6;           // / (IN_DIM/2)
        const int kk = idx & 63;
        const float2 f = ((const float2*)fc_w)[idx];
        const u32 w = ((u32)f2bf(f.y) << 16) | (u32)f2bf(f.x);
        *(u32*)&wlds[d][2 * kk] = w;
    }
    __syncthreads();

    if (wid < N_NODES / 16) {              // 3125 waves exactly
        const int n0 = wid * 16;

        // A-frags: lane holds h[n0+row][32*kc + 8*kq + j], j=0..7 (f32->bf16)
        bf16x8_t afr[4];
        const float* hrow = h + (size_t)(n0 + row) * IN_DIM + 8 * kq;
#pragma unroll
        for (int kc = 0; kc < 4; ++kc) {
            const float4 f0 = *(const float4*)(hrow + 32 * kc);
            const float4 f1 = *(const float4*)(hrow + 32 * kc + 4);
            bf16x8_t a;
            a[0] = (short)f2bf(f0.x); a[1] = (short)f2bf(f0.y);
            a[2] = (short)f2bf(f0.z); a[3] = (short)f2bf(f0.w);
            a[4] = (short)f2bf(f1.x); a[5] = (short)f2bf(f1.y);
            a[6] = (short)f2bf(f1.z); a[7] = (short)f2bf(f1.w);
            afr[kc] = a;
        }

        f32x4_t acc[4];
#pragma unroll
        for (int dt = 0; dt < 4; ++dt) {
            f32x4_t c = {0.f, 0.f, 0.f, 0.f};
#pragma unroll
            for (int kc = 0; kc < 4; ++kc) {
                const bf16x8_t bfr =
                    *(const bf16x8_t*)&wlds[dt * 16 + row][32 * kc + 8 * kq];
                c = __builtin_amdgcn_mfma_f32_16x16x32_bf16(afr[kc], bfr, c, 0, 0, 0);
            }
            acc[dt] = c;
        }

        // store z (bf16). D layout (m89): col = lane&15, row = 4*(lane>>4)+reg
#pragma unroll
        for (int dt = 0; dt < 4; ++dt)
#pragma unroll
            for (int r = 0; r < 4; ++r)
                zb[(size_t)(n0 + 4 * kq + r) * OUT_DIM + dt * 16 + row] = f2bf(acc[dt][r]);

        // attention scores: reduce over 4 dim-tiles x 16 lanes
        float a_s[4], a_d[4];
#pragma unroll
        for (int dt = 0; dt < 4; ++dt) {
            a_s[dt] = attn_w[dt * 16 + row];
            a_d[dt] = attn_w[OUT_DIM + dt * 16 + row];
        }
#pragma unroll
        for (int r = 0; r < 4; ++r) {
            float ps = 0.f, pd = 0.f;
#pragma unroll
            for (int dt = 0; dt < 4; ++dt) {
                ps = fmaf(acc[dt][r], a_s[dt], ps);
                pd = fmaf(acc[dt][r], a_d[dt], pd);
            }
#pragma unroll
            for (int mm = 1; mm < 16; mm <<= 1) {
                ps += __shfl_xor(ps, mm);
                pd += __shfl_xor(pd, mm);
            }
            if (row == 0) {
                const int n = n0 + 4 * kq + r;
                s_src[n] = ps;
                s_dst[n] = pd;
            }
        }
    }

    // ---- kernel tail: row_ptr[gt] = lower_bound(dst, gt) ----
    const int gt = blockIdx.x * 256 + tid;
    if (gt <= N_NODES) {
        int lo = 0, hi = N_EDGES;
        while (lo < hi) {
            const int mid = (lo + hi) >> 1;
            if (dst[mid] < gt) lo = mid + 1; else hi = mid;
        }
        row_ptr[gt] = lo;
    }
}

// Kernel B: 16-lane group per dst node (4 nodes/wave, 16 nodes/block).
// No max-subtraction (scores bounded ~5 -> exp <= ~150, f32-safe; the
// softmax ratio is mathematically identical). Single pass: p = exp(ev),
// per-lane denom accumulation, ONE 4-shfl reduce at the end.
// Gather: lane sub holds dims 4*sub..4*sub+3 (u64 read = 128B/group-edge;
// one wave VMEM instruction serves 4 edges across the 4 groups).
__global__ __launch_bounds__(256) void aggregate_kernel(
    const int* __restrict__ src, const int* __restrict__ row_ptr,
    const u16* __restrict__ zb, const float* __restrict__ s_src,
    const float* __restrict__ s_dst, float* __restrict__ out)
{
    const int tid = threadIdx.x;
    const int sub = tid & 15;                 // lane within group = dim quad
    const int n   = blockIdx.x * 16 + (tid >> 4);   // grid is exact: 3125*16

    const int e0 = row_ptr[n];
    const int e1 = row_ptr[n + 1];
    const float sdn = s_dst[n];

    float denom = 0.f;
    float acc0 = 0.f, acc1 = 0.f, acc2 = 0.f, acc3 = 0.f;

    for (int c0 = e0; c0 < e1; c0 += 16) {
        const int e = c0 + sub;
        const bool valid = e < e1;
        const int s_l = valid ? src[e] : 0;            // 64B coalesced/group
        float p = 0.f;
        if (valid) {
            float t = s_src[s_l] + sdn;
            t = (t > 0.f) ? t : t * NEG_SLOPE;
            p = __expf(t);
        }
        denom += p;

        const int cnt = (e1 - c0 < 16) ? (e1 - c0) : 16;
#pragma unroll 4
        for (int j = 0; j < cnt; ++j) {
            const float pj = __shfl(p, j, 16);
            const int   sj = __shfl(s_l, j, 16);
            const uint2 w = *(const uint2*)(zb + (size_t)sj * OUT_DIM + 4 * sub);
            acc0 = fmaf(pj, bflo(w.x), acc0);
            acc1 = fmaf(pj, bfhi(w.x), acc1);
            acc2 = fmaf(pj, bflo(w.y), acc2);
            acc3 = fmaf(pj, bfhi(w.y), acc3);
        }
    }

#pragma unroll
    for (int off = 1; off < 16; off <<= 1)
        denom += __shfl_xor(denom, off, 16);

    const float inv = (denom > 0.f) ? (1.f / denom) : 0.f;
    float4 o = make_float4(acc0 * inv, acc1 * inv, acc2 * inv, acc3 * inv);
    *(float4*)(out + (size_t)n * OUT_DIM + 4 * sub) = o;   // 256B/group
}

extern "C" void kernel_launch(void* const* d_in, const int* in_sizes, int n_in,
                              void* d_out, int out_size, void* d_ws, size_t ws_size,
                              hipStream_t stream)
{
    const float* h      = (const float*)d_in[0];
    const int*   src    = (const int*)  d_in[1];
    const int*   dst    = (const int*)  d_in[2];
    const float* fc_w   = (const float*)d_in[3];
    const float* attn_w = (const float*)d_in[4];
    float*       out    = (float*)d_out;

    char* ws = (char*)d_ws;
    u16* zb = (u16*)ws;                                           // 6.4 MB
    ws += ((size_t)N_NODES * OUT_DIM * sizeof(u16) + 255) & ~(size_t)255;
    float* s_src = (float*)ws;
    ws += ((size_t)N_NODES * sizeof(float) + 255) & ~(size_t)255;
    float* s_dst = (float*)ws;
    ws += ((size_t)N_NODES * sizeof(float) + 255) & ~(size_t)255;
    int* row_ptr = (int*)ws;
    (void)ws_size;

    const int gemm_blocks = (N_NODES / 16 + 3) / 4;               // 782
    gemm_fused_kernel<<<gemm_blocks, 256, 0, stream>>>(
        h, fc_w, attn_w, dst, zb, s_src, s_dst, row_ptr);
    aggregate_kernel<<<N_NODES / 16, 256, 0, stream>>>(           // 3125 blocks
        src, row_ptr, zb, s_src, s_dst, out);
}

// Round 8
// 38.276 us; speedup vs baseline: 18.6316x; 1.1838x over previous
//
#include <hip/hip_runtime.h>
#include <hip/hip_bf16.h>
#include <math.h>

#define N_NODES 50000
#define N_EDGES 800000
#define IN_DIM 128
#define OUT_DIM 64
#define NEG_SLOPE 0.01f
#define TILE_E 512

typedef unsigned short u16;
typedef unsigned int   u32;
typedef __attribute__((ext_vector_type(8))) short bf16x8_t;
typedef __attribute__((ext_vector_type(4))) float f32x4_t;

static __device__ __forceinline__ u16 f2bf(float x) {
    __hip_bfloat16 b = __float2bfloat16(x);      // hardware cvt (RNE on gfx950)
    return __builtin_bit_cast(u16, b);
}
static __device__ __forceinline__ float bflo(u32 w) { return __uint_as_float(w << 16); }
static __device__ __forceinline__ float bfhi(u32 w) { return __uint_as_float(w & 0xffff0000u); }

// Kernel A (fused) — UNCHANGED from R7 (clean A/B: only aggregate changes).
__global__ __launch_bounds__(256) void gemm_fused_kernel(
    const float* __restrict__ h, const float* __restrict__ fc_w,
    const float* __restrict__ attn_w, const int* __restrict__ dst,
    u16* __restrict__ zb, float* __restrict__ s_src, float* __restrict__ s_dst,
    int* __restrict__ row_ptr)
{
    __shared__ u16 wlds[OUT_DIM][IN_DIM + 8];   // 64 x 136 u16 = 17.4 KB

    const int tid  = threadIdx.x;
    const int lane = tid & 63;
    const int wid  = blockIdx.x * 4 + (tid >> 6);
    const int row  = lane & 15;
    const int kq   = lane >> 4;

    for (int idx = tid; idx < OUT_DIM * IN_DIM / 2; idx += 256) {
        const int d  = idx >> 6;
        const int kk = idx & 63;
        const float2 f = ((const float2*)fc_w)[idx];
        const u32 w = ((u32)f2bf(f.y) << 16) | (u32)f2bf(f.x);
        *(u32*)&wlds[d][2 * kk] = w;
    }
    __syncthreads();

    if (wid < N_NODES / 16) {
        const int n0 = wid * 16;

        bf16x8_t afr[4];
        const float* hrow = h + (size_t)(n0 + row) * IN_DIM + 8 * kq;
#pragma unroll
        for (int kc = 0; kc < 4; ++kc) {
            const float4 f0 = *(const float4*)(hrow + 32 * kc);
            const float4 f1 = *(const float4*)(hrow + 32 * kc + 4);
            bf16x8_t a;
            a[0] = (short)f2bf(f0.x); a[1] = (short)f2bf(f0.y);
            a[2] = (short)f2bf(f0.z); a[3] = (short)f2bf(f0.w);
            a[4] = (short)f2bf(f1.x); a[5] = (short)f2bf(f1.y);
            a[6] = (short)f2bf(f1.z); a[7] = (short)f2bf(f1.w);
            afr[kc] = a;
        }

        f32x4_t acc[4];
#pragma unroll
        for (int dt = 0; dt < 4; ++dt) {
            f32x4_t c = {0.f, 0.f, 0.f, 0.f};
#pragma unroll
            for (int kc = 0; kc < 4; ++kc) {
                const bf16x8_t bfr =
                    *(const bf16x8_t*)&wlds[dt * 16 + row][32 * kc + 8 * kq];
                c = __builtin_amdgcn_mfma_f32_16x16x32_bf16(afr[kc], bfr, c, 0, 0, 0);
            }
            acc[dt] = c;
        }

#pragma unroll
        for (int dt = 0; dt < 4; ++dt)
#pragma unroll
            for (int r = 0; r < 4; ++r)
                zb[(size_t)(n0 + 4 * kq + r) * OUT_DIM + dt * 16 + row] = f2bf(acc[dt][r]);

        float a_s[4], a_d[4];
#pragma unroll
        for (int dt = 0; dt < 4; ++dt) {
            a_s[dt] = attn_w[dt * 16 + row];
            a_d[dt] = attn_w[OUT_DIM + dt * 16 + row];
        }
#pragma unroll
        for (int r = 0; r < 4; ++r) {
            float ps = 0.f, pd = 0.f;
#pragma unroll
            for (int dt = 0; dt < 4; ++dt) {
                ps = fmaf(acc[dt][r], a_s[dt], ps);
                pd = fmaf(acc[dt][r], a_d[dt], pd);
            }
#pragma unroll
            for (int mm = 1; mm < 16; mm <<= 1) {
                ps += __shfl_xor(ps, mm);
                pd += __shfl_xor(pd, mm);
            }
            if (row == 0) {
                const int n = n0 + 4 * kq + r;
                s_src[n] = ps;
                s_dst[n] = pd;
            }
        }
    }

    const int gt = blockIdx.x * 256 + tid;
    if (gt <= N_NODES) {
        int lo = 0, hi = N_EDGES;
        while (lo < hi) {
            const int mid = (lo + hi) >> 1;
            if (dst[mid] < gt) lo = mid + 1; else hi = mid;
        }
        row_ptr[gt] = lo;
    }
}

// Kernel B (rewritten): two-phase per block of 16 nodes.
// Phase 1: all 256 threads score the block's contiguous edge span
// edge-parallel (coalesced src/dst reads, full-lane exp; dst read directly,
// since softmax needs no max-subtraction here) -> {src,p} staged in LDS.
// Phase 2: 16-lane group per node; per edge ONE broadcast ds_read_b64
// (address linear & known early -> deep load pipelining, no ds_bpermute)
// + one uint2 z-gather + fma. denom: all lanes accumulate the same pj ->
// no cross-lane reduction at all.
__global__ __launch_bounds__(256) void aggregate_kernel(
    const int* __restrict__ src, const int* __restrict__ dst,
    const int* __restrict__ row_ptr,
    const u16* __restrict__ zb, const float* __restrict__ s_src,
    const float* __restrict__ s_dst, float* __restrict__ out)
{
    __shared__ uint2 ep[TILE_E];     // {src, exp(score) bits} : 4 KB

    const int tid = threadIdx.x;
    const int g   = tid >> 4;        // group = node within block
    const int sub = tid & 15;        // dim quad
    const int nb  = blockIdx.x * 16;
    const int n   = nb + g;

    const int E0 = row_ptr[nb];
    const int E1 = row_ptr[nb + 16];
    const int e0 = row_ptr[n];
    const int e1 = row_ptr[n + 1];

    float denom = 0.f;
    float acc0 = 0.f, acc1 = 0.f, acc2 = 0.f, acc3 = 0.f;

    for (int t0 = E0; t0 < E1; t0 += TILE_E) {
        const int tend = (t0 + TILE_E < E1) ? (t0 + TILE_E) : E1;

        // ---- phase 1: edge-parallel scoring into LDS ----
        for (int idx = t0 + tid; idx < tend; idx += 256) {
            const int se = src[idx];                 // coalesced
            const int de = dst[idx];                 // coalesced (sorted)
            float t = s_src[se] + s_dst[de];
            t = (t > 0.f) ? t : t * NEG_SLOPE;
            ep[idx - t0] = make_uint2((u32)se, __float_as_uint(__expf(t)));
        }
        __syncthreads();

        // ---- phase 2: per-group gather over this node's slice of the tile ----
        const int l0 = ((e0 > t0) ? e0 : t0) - t0;
        const int l1 = ((e1 < tend) ? e1 : tend) - t0;
#pragma unroll 4
        for (int j = l0; j < l1; ++j) {
            const uint2 sp = ep[j];                  // broadcast ds_read_b64
            const float pj = __uint_as_float(sp.y);
            const uint2 w = *(const uint2*)(zb + (size_t)sp.x * OUT_DIM + 4 * sub);
            denom += pj;
            acc0 = fmaf(pj, bflo(w.x), acc0);
            acc1 = fmaf(pj, bfhi(w.x), acc1);
            acc2 = fmaf(pj, bflo(w.y), acc2);
            acc3 = fmaf(pj, bfhi(w.y), acc3);
        }
        __syncthreads();                             // LDS reuse across tiles
    }

    const float inv = (denom > 0.f) ? (1.f / denom) : 0.f;
    *(float4*)(out + (size_t)n * OUT_DIM + 4 * sub) =
        make_float4(acc0 * inv, acc1 * inv, acc2 * inv, acc3 * inv);
}

extern "C" void kernel_launch(void* const* d_in, const int* in_sizes, int n_in,
                              void* d_out, int out_size, void* d_ws, size_t ws_size,
                              hipStream_t stream)
{
    const float* h      = (const float*)d_in[0];
    const int*   src    = (const int*)  d_in[1];
    const int*   dst    = (const int*)  d_in[2];
    const float* fc_w   = (const float*)d_in[3];
    const float* attn_w = (const float*)d_in[4];
    float*       out    = (float*)d_out;

    char* ws = (char*)d_ws;
    u16* zb = (u16*)ws;                                           // 6.4 MB
    ws += ((size_t)N_NODES * OUT_DIM * sizeof(u16) + 255) & ~(size_t)255;
    float* s_src = (float*)ws;
    ws += ((size_t)N_NODES * sizeof(float) + 255) & ~(size_t)255;
    float* s_dst = (float*)ws;
    ws += ((size_t)N_NODES * sizeof(float) + 255) & ~(size_t)255;
    int* row_ptr = (int*)ws;
    (void)ws_size;

    const int gemm_blocks = (N_NODES / 16 + 3) / 4;               // 782
    gemm_fused_kernel<<<gemm_blocks, 256, 0, stream>>>(
        h, fc_w, attn_w, dst, zb, s_src, s_dst, row_ptr);
    aggregate_kernel<<<N_NODES / 16, 256, 0, stream>>>(           // 3125 blocks
        src, dst, row_ptr, zb, s_src, s_dst, out);
}

// Round 9
// 33.688 us; speedup vs baseline: 21.1691x; 1.1362x over previous
//
#include <hip/hip_runtime.h>
#include <hip/hip_bf16.h>
#include <math.h>

#define N_NODES 50000
#define N_EDGES 800000
#define IN_DIM 128
#define OUT_DIM 64
#define NEG_SLOPE 0.01f
#define TILE_E 768
#define AGG_NPB 32

typedef unsigned short u16;
typedef unsigned int   u32;
typedef __attribute__((ext_vector_type(8))) short bf16x8_t;
typedef __attribute__((ext_vector_type(4))) float f32x4_t;

static __device__ __forceinline__ u16 f2bf(float x) {
    __hip_bfloat16 b = __float2bfloat16(x);      // hardware cvt (RNE)
    return __builtin_bit_cast(u16, b);
}
static __device__ __forceinline__ float bflo(u32 w) { return __uint_as_float(w << 16); }
static __device__ __forceinline__ float bfhi(u32 w) { return __uint_as_float(w & 0xffff0000u); }

// Kernel A: MFMA gemm + scores (unchanged core) + edge-parallel row_ptr build
// (replaces 20-deep dependent binary search with O(1)-depth boundary scatter).
__global__ __launch_bounds__(256) void gemm_fused_kernel(
    const float* __restrict__ h, const float* __restrict__ fc_w,
    const float* __restrict__ attn_w, const int* __restrict__ dst,
    u16* __restrict__ zb, float* __restrict__ s_src, float* __restrict__ s_dst,
    int* __restrict__ row_ptr)
{
    __shared__ u16 wlds[OUT_DIM][IN_DIM + 8];   // 64 x 136 u16 = 17.4 KB

    const int tid  = threadIdx.x;
    const int lane = tid & 63;
    const int wid  = blockIdx.x * 4 + (tid >> 6);
    const int row  = lane & 15;
    const int kq   = lane >> 4;

    // stage + convert fc_w (conflict-free)
    for (int idx = tid; idx < OUT_DIM * IN_DIM / 2; idx += 256) {
        const int d  = idx >> 6;
        const int kk = idx & 63;
        const float2 f = ((const float2*)fc_w)[idx];
        const u32 w = ((u32)f2bf(f.y) << 16) | (u32)f2bf(f.x);
        *(u32*)&wlds[d][2 * kk] = w;
    }
    __syncthreads();

    if (wid < N_NODES / 16) {              // 3125 waves exactly
        const int n0 = wid * 16;

        bf16x8_t afr[4];
        const float* hrow = h + (size_t)(n0 + row) * IN_DIM + 8 * kq;
#pragma unroll
        for (int kc = 0; kc < 4; ++kc) {
            const float4 f0 = *(const float4*)(hrow + 32 * kc);
            const float4 f1 = *(const float4*)(hrow + 32 * kc + 4);
            bf16x8_t a;
            a[0] = (short)f2bf(f0.x); a[1] = (short)f2bf(f0.y);
            a[2] = (short)f2bf(f0.z); a[3] = (short)f2bf(f0.w);
            a[4] = (short)f2bf(f1.x); a[5] = (short)f2bf(f1.y);
            a[6] = (short)f2bf(f1.z); a[7] = (short)f2bf(f1.w);
            afr[kc] = a;
        }

        f32x4_t acc[4];
#pragma unroll
        for (int dt = 0; dt < 4; ++dt) {
            f32x4_t c = {0.f, 0.f, 0.f, 0.f};
#pragma unroll
            for (int kc = 0; kc < 4; ++kc) {
                const bf16x8_t bfr =
                    *(const bf16x8_t*)&wlds[dt * 16 + row][32 * kc + 8 * kq];
                c = __builtin_amdgcn_mfma_f32_16x16x32_bf16(afr[kc], bfr, c, 0, 0, 0);
            }
            acc[dt] = c;
        }

        // store z (bf16). D layout (m89): col = lane&15, row = 4*(lane>>4)+reg
#pragma unroll
        for (int dt = 0; dt < 4; ++dt)
#pragma unroll
            for (int r = 0; r < 4; ++r)
                zb[(size_t)(n0 + 4 * kq + r) * OUT_DIM + dt * 16 + row] = f2bf(acc[dt][r]);

        float a_s[4], a_d[4];
#pragma unroll
        for (int dt = 0; dt < 4; ++dt) {
            a_s[dt] = attn_w[dt * 16 + row];
            a_d[dt] = attn_w[OUT_DIM + dt * 16 + row];
        }
#pragma unroll
        for (int r = 0; r < 4; ++r) {
            float ps = 0.f, pd = 0.f;
#pragma unroll
            for (int dt = 0; dt < 4; ++dt) {
                ps = fmaf(acc[dt][r], a_s[dt], ps);
                pd = fmaf(acc[dt][r], a_d[dt], pd);
            }
#pragma unroll
            for (int mm = 1; mm < 16; mm <<= 1) {
                ps += __shfl_xor(ps, mm);
                pd += __shfl_xor(pd, mm);
            }
            if (row == 0) {
                const int n = n0 + 4 * kq + r;
                s_src[n] = ps;
                s_dst[n] = pd;
            }
        }
    }

    // ---- row_ptr boundary build: thread t covers edges [4t, 4t+4) ----
    const int t = blockIdx.x * 256 + tid;
    if (t < N_EDGES / 4) {
        const int eb = 4 * t;
        const int4 d4 = *(const int4*)(dst + eb);       // coalesced
        int prev = (eb == 0) ? -1 : dst[eb - 1];
        const int dd[4] = {d4.x, d4.y, d4.z, d4.w};
#pragma unroll
        for (int k = 0; k < 4; ++k) {
            const int cur = dd[k];
            for (int n = prev + 1; n <= cur; ++n) row_ptr[n] = eb + k;  // rare
            prev = cur;
        }
        if (eb + 4 == N_EDGES)
            for (int n = prev + 1; n <= N_NODES; ++n) row_ptr[n] = N_EDGES;
    }
}

// Kernel B: 32 nodes/block, 8-lane group per node (8 dims/lane).
// Phase 1: edge-parallel scoring into LDS {src, p} (coalesced, full-lane exp).
// Phase 2: per-group walk: ds_read_b64 broadcast + ONE uint4 z-gather
// (8 edges per wave VMEM instr) + 8 independent fma chains. No cross-lane
// reduction anywhere (denom accumulated redundantly per lane).
__global__ __launch_bounds__(256) void aggregate_kernel(
    const int* __restrict__ src, const int* __restrict__ dst,
    const int* __restrict__ row_ptr,
    const u16* __restrict__ zb, const float* __restrict__ s_src,
    const float* __restrict__ s_dst, float* __restrict__ out)
{
    __shared__ uint2 ep[TILE_E];     // {src, exp(score) bits} : 6 KB

    const int tid = threadIdx.x;
    const int g   = tid >> 3;        // group = node within block (0..31)
    const int sub = tid & 7;         // dim octet (dims 8*sub .. 8*sub+7)
    const int nb  = blockIdx.x * AGG_NPB;
    const int n   = nb + g;
    const int ntop = (nb + AGG_NPB < N_NODES) ? (nb + AGG_NPB) : N_NODES;

    const int E0 = row_ptr[nb];
    const int E1 = row_ptr[ntop];
    const bool act = n < N_NODES;
    const int e0 = act ? row_ptr[n] : E1;
    const int e1 = act ? row_ptr[n + 1] : E1;

    float denom = 0.f;
    float a0 = 0.f, a1 = 0.f, a2 = 0.f, a3 = 0.f;
    float a4 = 0.f, a5 = 0.f, a6 = 0.f, a7 = 0.f;

    for (int t0 = E0; t0 < E1; t0 += TILE_E) {
        const int tend = (t0 + TILE_E < E1) ? (t0 + TILE_E) : E1;

        __syncthreads();                          // ep safe to overwrite
        for (int idx = t0 + tid; idx < tend; idx += 256) {
            const int se = src[idx];              // coalesced
            const int de = dst[idx];              // coalesced (sorted -> L1)
            float tt = s_src[se] + s_dst[de];
            tt = (tt > 0.f) ? tt : tt * NEG_SLOPE;
            ep[idx - t0] = make_uint2((u32)se, __float_as_uint(__expf(tt)));
        }
        __syncthreads();

        const int l0 = ((e0 > t0) ? e0 : t0) - t0;
        const int l1 = ((e1 < tend) ? e1 : tend) - t0;
#pragma unroll 4
        for (int j = l0; j < l1; ++j) {
            const uint2 sp = ep[j];               // broadcast ds_read_b64
            const float pj = __uint_as_float(sp.y);
            const uint4 w = *(const uint4*)(zb + (size_t)sp.x * OUT_DIM + 8 * sub);
            denom += pj;
            a0 = fmaf(pj, bflo(w.x), a0);  a1 = fmaf(pj, bfhi(w.x), a1);
            a2 = fmaf(pj, bflo(w.y), a2);  a3 = fmaf(pj, bfhi(w.y), a3);
            a4 = fmaf(pj, bflo(w.z), a4);  a5 = fmaf(pj, bfhi(w.z), a5);
            a6 = fmaf(pj, bflo(w.w), a6);  a7 = fmaf(pj, bfhi(w.w), a7);
        }
    }

    if (act) {
        const float inv = (denom > 0.f) ? (1.f / denom) : 0.f;
        float* op = out + (size_t)n * OUT_DIM + 8 * sub;
        *(float4*)(op)     = make_float4(a0 * inv, a1 * inv, a2 * inv, a3 * inv);
        *(float4*)(op + 4) = make_float4(a4 * inv, a5 * inv, a6 * inv, a7 * inv);
    }
}

extern "C" void kernel_launch(void* const* d_in, const int* in_sizes, int n_in,
                              void* d_out, int out_size, void* d_ws, size_t ws_size,
                              hipStream_t stream)
{
    const float* h      = (const float*)d_in[0];
    const int*   src    = (const int*)  d_in[1];
    const int*   dst    = (const int*)  d_in[2];
    const float* fc_w   = (const float*)d_in[3];
    const float* attn_w = (const float*)d_in[4];
    float*       out    = (float*)d_out;

    char* ws = (char*)d_ws;
    u16* zb = (u16*)ws;                                           // 6.4 MB
    ws += ((size_t)N_NODES * OUT_DIM * sizeof(u16) + 255) & ~(size_t)255;
    float* s_src = (float*)ws;
    ws += ((size_t)N_NODES * sizeof(float) + 255) & ~(size_t)255;
    float* s_dst = (float*)ws;
    ws += ((size_t)N_NODES * sizeof(float) + 255) & ~(size_t)255;
    int* row_ptr = (int*)ws;
    (void)ws_size;

    const int gemm_blocks = (N_NODES / 16 + 3) / 4;               // 782
    gemm_fused_kernel<<<gemm_blocks, 256, 0, stream>>>(
        h, fc_w, attn_w, dst, zb, s_src, s_dst, row_ptr);
    const int agg_blocks = (N_NODES + AGG_NPB - 1) / AGG_NPB;     // 1563
    aggregate_kernel<<<agg_blocks, 256, 0, stream>>>(
        src, dst, row_ptr, zb, s_src, s_dst, out);
}